// Round 1
// 218.591 us; speedup vs baseline: 1.0493x; 1.0493x over previous
//
#include <hip/hip_runtime.h>
#include <stdint.h>

// Problem constants: T_OBS=8, T_PRE=12, B=524288, IN=2, E=16, H=8
#define T_OBS 8
#define T_PRE 12
#define BATCH 524288

#define NLOG2E  (-1.4426950408889634f)   // -log2(e): sigmoid prescale
#define P2LOG2E ( 2.8853900817779268f)   // +2*log2(e): tanh prescale

typedef __fp16 half8  __attribute__((ext_vector_type(8)));
typedef float  floatx16 __attribute__((ext_vector_type(16)));
typedef unsigned int uint_t;

__device__ __forceinline__ uint_t upk(float a, float b) {
    return __builtin_bit_cast(uint_t, __builtin_amdgcn_cvt_pkrtz(a, b));
}

// ---------------------------------------------------------------------------
// Weight prep -> per-lane MFMA A-fragments for v_mfma_f32_32x32x16_f16.
// A matrix: [M=32 gate rows (i0-7,f0-7,g0-7,o0-7)] x [K=16].
// SYMMETRIC half-lane layout (no cross-lane exchange needed in the step):
//   lower half supplies k0..7  = (x0, x1, h0, h1, h2, h3, 1, 0)
//   upper half supplies k8..15 = (x0, x1, h4, h5, h6, h7, 1, 0)
// so the A rows are:
//   k0,1  : folded input weights (W_ih @ W_in) * 0.5   (x contributes twice)
//   k2..5 : W_hh[:,0..3]
//   k6    : folded bias * 0.5                          (bias slot = 1.0 twice)
//   k7    : 0
//   k8,9  : folded input weights * 0.5
//   k10..13: W_hh[:,4..7]
//   k14   : folded bias * 0.5
//   k15   : 0
// Sigmoid rows (i,f,o) scaled by -log2e; tanh rows (g) by +2log2e.
// A-fragment layout: lane l holds A[m=l&31][k=(l>>5)*8 + j], j=0..7,
// packed as 4 dwords (f16 pairs). ws layout: uint[phase*256 + lane*4 + r].
// ---------------------------------------------------------------------------
__global__ void prep_weights(const float* __restrict__ W_in,
                             const float* __restrict__ b_in,
                             const float* __restrict__ W_ih_obs,
                             const float* __restrict__ W_hh_obs,
                             const float* __restrict__ b_ih_obs,
                             const float* __restrict__ b_hh_obs,
                             const float* __restrict__ W_ih_pre,
                             const float* __restrict__ W_hh_pre,
                             const float* __restrict__ b_ih_pre,
                             const float* __restrict__ b_hh_pre,
                             uint_t* __restrict__ wsu) {
    int t = threadIdx.x;            // 0..127: phase*64 + lane
    int phase = t >> 6;
    int l = t & 63;
    int m = l & 31;                 // gate row
    int kh = l >> 5;                // k-half: 0 -> k0..7, 1 -> k8..15
    const float* W_ih = phase ? W_ih_pre : W_ih_obs;
    const float* W_hh = phase ? W_hh_pre : W_hh_obs;
    const float* b_ih = phase ? b_ih_pre : b_ih_obs;
    const float* b_hh = phase ? b_hh_pre : b_hh_obs;

    float wx0 = 0.f, wx1 = 0.f;
    float bb = b_ih[m] + b_hh[m];
    #pragma unroll
    for (int e = 0; e < 16; e++) {
        float wie = W_ih[m * 16 + e];
        wx0 += wie * W_in[e * 2 + 0];
        wx1 += wie * W_in[e * 2 + 1];
        bb  += wie * b_in[e];
    }
    float s = (m >= 16 && m < 24) ? P2LOG2E : NLOG2E;

    float af[16];
    af[0] = wx0 * s * 0.5f;          // x slots appear in BOTH k-halves:
    af[1] = wx1 * s * 0.5f;          // half weight each (exact in f16)
    #pragma unroll
    for (int j = 0; j < 4; j++) af[2 + j] = W_hh[m * 8 + j] * s;
    af[6] = bb * s * 0.5f;
    af[7] = 0.f;
    af[8] = af[0];
    af[9] = af[1];
    #pragma unroll
    for (int j = 0; j < 4; j++) af[10 + j] = W_hh[m * 8 + 4 + j] * s;
    af[14] = af[6];
    af[15] = 0.f;

    #pragma unroll
    for (int r = 0; r < 4; r++)
        wsu[phase * 256 + l * 4 + r] = upk(af[kh * 8 + 2 * r], af[kh * 8 + 2 * r + 1]);
}

// ---------------------------------------------------------------------------
// One LSTM step for 32 batch elements per wave via a single 32x32x16 MFMA.
// Lane n (n<32) owns units 0-3 of batch col n; lane n+32 owns units 4-7.
// B fragment is IDENTICAL in shape for both halves (no shfl, no cndmask):
//   bu = { (x0,x1), (hA,hB), (hC,hD), (1.0, 0) }
// Activations use combined denominators (algebraically identical to
// sigmoid/tanh, 7 trans ops per unit-step instead of 10):
//   cn = [c*(1+ei)(1+eg) + (eg-1)(1+ef)] / [(1+ei)(1+ef)(1+eg)]
//   h  = (ec-1) / [(1+eo)(1+ec)],  ec = exp2(2*log2e*cn)
// where ei=exp2(-i*log2e) etc. come prescaled out of the MFMA.
// ---------------------------------------------------------------------------
__device__ __forceinline__ void lstm_step(half8 A, uint_t xpk,
                                          uint_t& pk0, uint_t& pk1,
                                          float c[4], float h[4],
                                          const floatx16& zacc) {
    uint4 bu;
    bu.x = xpk;               // k0,1  | k8,9   : x0, x1
    bu.y = pk0;               // k2,3  | k10,11 : h0,h1 | h4,h5
    bu.z = pk1;               // k4,5  | k12,13 : h2,h3 | h6,h7
    bu.w = 0x00003C00u;       // k6,7  | k14,15 : 1.0, 0 (bias slot)
    half8 B = __builtin_bit_cast(half8, bu);

    floatx16 d = __builtin_amdgcn_mfma_f32_32x32x16_f16(A, B, zacc, 0, 0, 0);

    // D rows for this lane: reg j -> i-unit, 4+j -> f, 8+j -> g, 12+j -> o
    #pragma unroll
    for (int j = 0; j < 4; j++) {
        float ei = __builtin_amdgcn_exp2f(d[j]);          // e^{-i}
        float ef = __builtin_amdgcn_exp2f(d[4 + j]);      // e^{-f}
        float eg = __builtin_amdgcn_exp2f(d[8 + j]);      // e^{2g}
        float eo = __builtin_amdgcn_exp2f(d[12 + j]);     // e^{-o}
        float ai  = 1.f + ei;
        float afv = 1.f + ef;
        float ag  = 1.f + eg;
        float gm  = eg - 1.f;
        float p   = ai * ag;
        float num = __builtin_fmaf(c[j], p, gm * afv);
        float cn  = num * __builtin_amdgcn_rcpf(p * afv);
        c[j] = cn;
        float ec = __builtin_amdgcn_exp2f(P2LOG2E * cn);  // e^{2*cn}
        h[j] = (ec - 1.f) * __builtin_amdgcn_rcpf((1.f + eo) * (1.f + ec));
    }
    pk0 = upk(h[0], h[1]);
    pk1 = upk(h[2], h[3]);
}

__global__ __launch_bounds__(256, 2)
void lstm_encoder(const float2* __restrict__ obs,
                  const float2* __restrict__ pre,
                  const float4* __restrict__ h0,
                  const float4* __restrict__ c0,
                  const float4* __restrict__ c0p,
                  const uint4* __restrict__ wf,
                  float* __restrict__ out) {
    const int tid  = threadIdx.x;
    const int lane = tid & 63;
    const int wv   = tid >> 6;              // wave in block: 0..3
    const int n    = lane & 31;             // batch col within tile
    const int half = lane >> 5;             // 0: units 0-3, 1: units 4-7
    const size_t nb = (size_t)blockIdx.x * 128 + wv * 32 + n;

    half8 Aobs = __builtin_bit_cast(half8, wf[lane]);
    half8 Apre = __builtin_bit_cast(half8, wf[64 + lane]);

    floatx16 zacc;
    #pragma unroll
    for (int i = 0; i < 16; i++) zacc[i] = 0.f;

    // init: this lane's 4 units of h and c; hoist the c0_pre load too so its
    // latency hides under the whole obs phase.
    float4 hv  = h0[nb * 2 + half];
    float4 cv  = c0[nb * 2 + half];
    float4 cv2 = c0p[nb * 2 + half];
    float c[4] = {cv.x, cv.y, cv.z, cv.w};
    float h[4] = {hv.x, hv.y, hv.z, hv.w};
    uint_t pk0 = upk(h[0], h[1]);
    uint_t pk1 = upk(h[2], h[3]);

    // 1-deep x prefetch: next step's load issues before this step's math.
    float2 xv = obs[nb];
    #pragma unroll 1
    for (int t = 0; t < T_OBS - 1; t++) {
        float2 xn = obs[(size_t)(t + 1) * BATCH + nb];
        lstm_step(Aobs, upk(xv.x, xv.y), pk0, pk1, c, h, zacc);
        xv = xn;
    }
    {   // last obs step; prefetch first pre step
        float2 xn = pre[nb];
        lstm_step(Aobs, upk(xv.x, xv.y), pk0, pk1, c, h, zacc);
        xv = xn;
    }

    // c_out (transpose-then-reshape): out[u*B + b] = h[b][u]
    #pragma unroll
    for (int j = 0; j < 4; j++)
        out[(size_t)(half * 4 + j) * BATCH + nb] = h[j];

    // pre phase: h carries over, c re-initialized
    c[0] = cv2.x; c[1] = cv2.y; c[2] = cv2.z; c[3] = cv2.w;

    #pragma unroll 1
    for (int t = 0; t < T_PRE - 1; t++) {
        float2 xn = pre[(size_t)(t + 1) * BATCH + nb];
        lstm_step(Apre, upk(xv.x, xv.y), pk0, pk1, c, h, zacc);
        xv = xn;
    }
    lstm_step(Apre, upk(xv.x, xv.y), pk0, pk1, c, h, zacc);

    #pragma unroll
    for (int j = 0; j < 4; j++)
        out[(size_t)(8 + half * 4 + j) * BATCH + nb] = h[j];
}

extern "C" void kernel_launch(void* const* d_in, const int* in_sizes, int n_in,
                              void* d_out, int out_size, void* d_ws, size_t ws_size,
                              hipStream_t stream) {
    prep_weights<<<1, 128, 0, stream>>>(
        (const float*)d_in[5],  (const float*)d_in[6],
        (const float*)d_in[7],  (const float*)d_in[8],
        (const float*)d_in[9],  (const float*)d_in[10],
        (const float*)d_in[11], (const float*)d_in[12],
        (const float*)d_in[13], (const float*)d_in[14],
        (uint_t*)d_ws);

    lstm_encoder<<<BATCH / 128, 256, 0, stream>>>(
        (const float2*)d_in[0], (const float2*)d_in[1],
        (const float4*)d_in[2], (const float4*)d_in[3], (const float4*)d_in[4],
        (const uint4*)d_ws, (float*)d_out);
}

// Round 2
// 212.008 us; speedup vs baseline: 1.0819x; 1.0311x over previous
//
#include <hip/hip_runtime.h>
#include <stdint.h>

// Problem constants: T_OBS=8, T_PRE=12, B=524288, IN=2, E=16, H=8
#define T_OBS 8
#define T_PRE 12
#define BATCH 524288

#define NLOG2E  (-1.4426950408889634f)   // -log2(e): sigmoid prescale
#define P2LOG2E ( 2.8853900817779268f)   // +2*log2(e): tanh prescale

typedef __fp16 half8  __attribute__((ext_vector_type(8)));
typedef float  floatx16 __attribute__((ext_vector_type(16)));
typedef float  f32x2   __attribute__((ext_vector_type(2)));
typedef unsigned int uint_t;

__device__ __forceinline__ uint_t upk(float a, float b) {
    return __builtin_bit_cast(uint_t, __builtin_amdgcn_cvt_pkrtz(a, b));
}

// ---------------------------------------------------------------------------
// Weight prep -> per-lane MFMA A-fragments for v_mfma_f32_32x32x16_f16.
// A matrix: [M=32 gate rows (i0-7,f0-7,g0-7,o0-7)] x [K=16].
// SYMMETRIC half-lane layout (no cross-lane exchange needed in the step):
//   lower half supplies k0..7  = (x0, x1, h0, h1, h2, h3, 1, 0)
//   upper half supplies k8..15 = (x0, x1, h4, h5, h6, h7, 1, 0)
// A rows: k0,1/k8,9 = folded (W_ih@W_in)*0.5 ; k2..5/k10..13 = W_hh cols ;
//         k6/k14 = folded bias*0.5 ; k7/k15 = 0.
// Sigmoid rows (i,f,o) scaled by -log2e; tanh rows (g) by +2log2e.
// A-fragment layout: lane l holds A[m=l&31][k=(l>>5)*8 + j], j=0..7,
// packed as 4 dwords (f16 pairs). ws layout: uint[phase*256 + lane*4 + r].
// ---------------------------------------------------------------------------
__global__ void prep_weights(const float* __restrict__ W_in,
                             const float* __restrict__ b_in,
                             const float* __restrict__ W_ih_obs,
                             const float* __restrict__ W_hh_obs,
                             const float* __restrict__ b_ih_obs,
                             const float* __restrict__ b_hh_obs,
                             const float* __restrict__ W_ih_pre,
                             const float* __restrict__ W_hh_pre,
                             const float* __restrict__ b_ih_pre,
                             const float* __restrict__ b_hh_pre,
                             uint_t* __restrict__ wsu) {
    int t = threadIdx.x;            // 0..127: phase*64 + lane
    int phase = t >> 6;
    int l = t & 63;
    int m = l & 31;                 // gate row
    int kh = l >> 5;                // k-half: 0 -> k0..7, 1 -> k8..15
    const float* W_ih = phase ? W_ih_pre : W_ih_obs;
    const float* W_hh = phase ? W_hh_pre : W_hh_obs;
    const float* b_ih = phase ? b_ih_pre : b_ih_obs;
    const float* b_hh = phase ? b_hh_pre : b_hh_obs;

    float wx0 = 0.f, wx1 = 0.f;
    float bb = b_ih[m] + b_hh[m];
    #pragma unroll
    for (int e = 0; e < 16; e++) {
        float wie = W_ih[m * 16 + e];
        wx0 += wie * W_in[e * 2 + 0];
        wx1 += wie * W_in[e * 2 + 1];
        bb  += wie * b_in[e];
    }
    float s = (m >= 16 && m < 24) ? P2LOG2E : NLOG2E;

    float af[16];
    af[0] = wx0 * s * 0.5f;          // x slots appear in BOTH k-halves:
    af[1] = wx1 * s * 0.5f;          // half weight each (exact in f16)
    #pragma unroll
    for (int j = 0; j < 4; j++) af[2 + j] = W_hh[m * 8 + j] * s;
    af[6] = bb * s * 0.5f;
    af[7] = 0.f;
    af[8] = af[0];
    af[9] = af[1];
    #pragma unroll
    for (int j = 0; j < 4; j++) af[10 + j] = W_hh[m * 8 + 4 + j] * s;
    af[14] = af[6];
    af[15] = 0.f;

    #pragma unroll
    for (int r = 0; r < 4; r++)
        wsu[phase * 256 + l * 4 + r] = upk(af[kh * 8 + 2 * r], af[kh * 8 + 2 * r + 1]);
}

// ---------------------------------------------------------------------------
// Activation math on unit-PAIRS as <2 x float> so clang lowers the full-rate
// ops to v_pk_{add,mul,fma}_f32 (2 f32/inst on gfx90a+). Trans ops (exp2/rcp)
// have no packed form and stay scalar: 7 per unit (4 gate exp2 + tanh(c) exp2
// + 2 combined-denominator rcp), same count as before.
//   cn = [c*(1+ei)(1+eg) + (eg-1)(1+ef)] / [(1+ei)(1+ef)(1+eg)]
//   h  = (ec-1) / [(1+eo)(1+ec)],  ec = exp2(2*log2e*cn)
// ---------------------------------------------------------------------------
__device__ __forceinline__ f32x2 exp2v(f32x2 a) {
    f32x2 r;
    r.x = __builtin_amdgcn_exp2f(a.x);
    r.y = __builtin_amdgcn_exp2f(a.y);
    return r;
}
__device__ __forceinline__ f32x2 rcpv(f32x2 a) {
    f32x2 r;
    r.x = __builtin_amdgcn_rcpf(a.x);
    r.y = __builtin_amdgcn_rcpf(a.y);
    return r;
}

__device__ __forceinline__ void act_pair(f32x2 gi, f32x2 gf, f32x2 gg, f32x2 go,
                                         f32x2& c, f32x2& h) {
    f32x2 ei = exp2v(gi);             // e^{-i}
    f32x2 ef = exp2v(gf);             // e^{-f}
    f32x2 eg = exp2v(gg);             // e^{2g}
    f32x2 eo = exp2v(go);             // e^{-o}
    f32x2 ai = ei + 1.f;
    f32x2 af = ef + 1.f;
    f32x2 ag = eg + 1.f;
    f32x2 gm = eg - 1.f;
    f32x2 p  = ai * ag;
    f32x2 num = c * p + gm * af;
    f32x2 cn  = num * rcpv(p * af);
    c = cn;
    f32x2 ec = exp2v(P2LOG2E * cn);   // e^{2*cn}
    h = (ec - 1.f) * rcpv((eo + 1.f) * (ec + 1.f));
}

// Per-wave-tile LSTM state: 32 batch cols, this lane owns 4 units of col n.
struct Tile {
    f32x2 c01, c23;   // cell state, units (0,1)/(2,3) of this lane's half
    f32x2 h01, h23;   // hidden state
    uint_t pk0, pk1;  // h packed to f16 pairs for the next B fragment
};

// One LSTM step for one 32-batch tile via a single 32x32x16 MFMA.
// B fragment is identical in shape for both lane halves (no shfl/cndmask):
//   bu = { (x0,x1), (hA,hB), (hC,hD), (1.0, 0) }
__device__ __forceinline__ void lstm_step(half8 A, uint_t xpk, Tile& T,
                                          const floatx16& zacc) {
    uint4 bu;
    bu.x = xpk;               // k0,1  | k8,9   : x0, x1
    bu.y = T.pk0;             // k2,3  | k10,11 : h0,h1 | h4,h5
    bu.z = T.pk1;             // k4,5  | k12,13 : h2,h3 | h6,h7
    bu.w = 0x00003C00u;       // k6,7  | k14,15 : 1.0, 0 (bias slot)
    half8 B = __builtin_bit_cast(half8, bu);

    floatx16 d = __builtin_amdgcn_mfma_f32_32x32x16_f16(A, B, zacc, 0, 0, 0);

    // D rows for this lane: reg j -> i-unit j, 4+j -> f, 8+j -> g, 12+j -> o
    f32x2 gi, gf, gg, go;
    gi.x = d[0];  gi.y = d[1];
    gf.x = d[4];  gf.y = d[5];
    gg.x = d[8];  gg.y = d[9];
    go.x = d[12]; go.y = d[13];
    act_pair(gi, gf, gg, go, T.c01, T.h01);
    gi.x = d[2];  gi.y = d[3];
    gf.x = d[6];  gf.y = d[7];
    gg.x = d[10]; gg.y = d[11];
    go.x = d[14]; go.y = d[15];
    act_pair(gi, gf, gg, go, T.c23, T.h23);

    T.pk0 = upk(T.h01.x, T.h01.y);
    T.pk1 = upk(T.h23.x, T.h23.y);
}

// ---------------------------------------------------------------------------
// TWO 32-batch tiles per wave (ILP x2): the two tiles' dependency chains
// (MFMA -> exp2 -> rcp -> exp2 -> cvt_pk -> next MFMA) interleave in the
// scheduler, filling the trans-latency stalls that capped VALUBusy at ~71%.
// Block = 256 threads = 4 waves = 256 batch; grid = BATCH/256.
// ---------------------------------------------------------------------------
__global__ __launch_bounds__(256, 4)
void lstm_encoder(const float2* __restrict__ obs,
                  const float2* __restrict__ pre,
                  const float4* __restrict__ h0,
                  const float4* __restrict__ c0,
                  const float4* __restrict__ c0p,
                  const uint4* __restrict__ wf,
                  float* __restrict__ out) {
    const int tid  = threadIdx.x;
    const int lane = tid & 63;
    const int wv   = tid >> 6;              // wave in block: 0..3
    const int n    = lane & 31;             // batch col within tile
    const int half = lane >> 5;             // 0: units 0-3, 1: units 4-7
    const size_t nbA = (size_t)blockIdx.x * 256 + wv * 64 + n;
    const size_t nbB = nbA + 32;

    half8 Aobs = __builtin_bit_cast(half8, wf[lane]);
    half8 Apre = __builtin_bit_cast(half8, wf[64 + lane]);

    floatx16 zacc;
    #pragma unroll
    for (int i = 0; i < 16; i++) zacc[i] = 0.f;

    Tile TA, TB;
    {
        float4 hvA = h0[nbA * 2 + half];
        float4 cvA = c0[nbA * 2 + half];
        float4 hvB = h0[nbB * 2 + half];
        float4 cvB = c0[nbB * 2 + half];
        TA.c01.x = cvA.x; TA.c01.y = cvA.y; TA.c23.x = cvA.z; TA.c23.y = cvA.w;
        TB.c01.x = cvB.x; TB.c01.y = cvB.y; TB.c23.x = cvB.z; TB.c23.y = cvB.w;
        TA.pk0 = upk(hvA.x, hvA.y); TA.pk1 = upk(hvA.z, hvA.w);
        TB.pk0 = upk(hvB.x, hvB.y); TB.pk1 = upk(hvB.z, hvB.w);
    }
    // hoist c0_pre loads: latency hides under the whole obs phase
    float4 cvA2 = c0p[nbA * 2 + half];
    float4 cvB2 = c0p[nbB * 2 + half];

    // 1-deep x prefetch: next step's loads issue before this step's math.
    float2 xvA = obs[nbA];
    float2 xvB = obs[nbB];
    #pragma unroll 1
    for (int t = 0; t < T_OBS - 1; t++) {
        float2 xnA = obs[(size_t)(t + 1) * BATCH + nbA];
        float2 xnB = obs[(size_t)(t + 1) * BATCH + nbB];
        lstm_step(Aobs, upk(xvA.x, xvA.y), TA, zacc);
        lstm_step(Aobs, upk(xvB.x, xvB.y), TB, zacc);
        xvA = xnA; xvB = xnB;
    }
    {   // last obs step; prefetch first pre step
        float2 xnA = pre[nbA];
        float2 xnB = pre[nbB];
        lstm_step(Aobs, upk(xvA.x, xvA.y), TA, zacc);
        lstm_step(Aobs, upk(xvB.x, xvB.y), TB, zacc);
        xvA = xnA; xvB = xnB;
    }

    // c_out (transpose-then-reshape): out[u*B + b] = h[b][u]
    out[(size_t)(half * 4 + 0) * BATCH + nbA] = TA.h01.x;
    out[(size_t)(half * 4 + 1) * BATCH + nbA] = TA.h01.y;
    out[(size_t)(half * 4 + 2) * BATCH + nbA] = TA.h23.x;
    out[(size_t)(half * 4 + 3) * BATCH + nbA] = TA.h23.y;
    out[(size_t)(half * 4 + 0) * BATCH + nbB] = TB.h01.x;
    out[(size_t)(half * 4 + 1) * BATCH + nbB] = TB.h01.y;
    out[(size_t)(half * 4 + 2) * BATCH + nbB] = TB.h23.x;
    out[(size_t)(half * 4 + 3) * BATCH + nbB] = TB.h23.y;

    // pre phase: h carries over, c re-initialized
    TA.c01.x = cvA2.x; TA.c01.y = cvA2.y; TA.c23.x = cvA2.z; TA.c23.y = cvA2.w;
    TB.c01.x = cvB2.x; TB.c01.y = cvB2.y; TB.c23.x = cvB2.z; TB.c23.y = cvB2.w;

    #pragma unroll 1
    for (int t = 0; t < T_PRE - 1; t++) {
        float2 xnA = pre[(size_t)(t + 1) * BATCH + nbA];
        float2 xnB = pre[(size_t)(t + 1) * BATCH + nbB];
        lstm_step(Apre, upk(xvA.x, xvA.y), TA, zacc);
        lstm_step(Apre, upk(xvB.x, xvB.y), TB, zacc);
        xvA = xnA; xvB = xnB;
    }
    lstm_step(Apre, upk(xvA.x, xvA.y), TA, zacc);
    lstm_step(Apre, upk(xvB.x, xvB.y), TB, zacc);

    out[(size_t)(8 + half * 4 + 0) * BATCH + nbA] = TA.h01.x;
    out[(size_t)(8 + half * 4 + 1) * BATCH + nbA] = TA.h01.y;
    out[(size_t)(8 + half * 4 + 2) * BATCH + nbA] = TA.h23.x;
    out[(size_t)(8 + half * 4 + 3) * BATCH + nbA] = TA.h23.y;
    out[(size_t)(8 + half * 4 + 0) * BATCH + nbB] = TB.h01.x;
    out[(size_t)(8 + half * 4 + 1) * BATCH + nbB] = TB.h01.y;
    out[(size_t)(8 + half * 4 + 2) * BATCH + nbB] = TB.h23.x;
    out[(size_t)(8 + half * 4 + 3) * BATCH + nbB] = TB.h23.y;
}

extern "C" void kernel_launch(void* const* d_in, const int* in_sizes, int n_in,
                              void* d_out, int out_size, void* d_ws, size_t ws_size,
                              hipStream_t stream) {
    prep_weights<<<1, 128, 0, stream>>>(
        (const float*)d_in[5],  (const float*)d_in[6],
        (const float*)d_in[7],  (const float*)d_in[8],
        (const float*)d_in[9],  (const float*)d_in[10],
        (const float*)d_in[11], (const float*)d_in[12],
        (const float*)d_in[13], (const float*)d_in[14],
        (uint_t*)d_ws);

    lstm_encoder<<<BATCH / 256, 256, 0, stream>>>(
        (const float2*)d_in[0], (const float2*)d_in[1],
        (const float4*)d_in[2], (const float4*)d_in[3], (const float4*)d_in[4],
        (const uint4*)d_ws, (float*)d_out);
}